// Round 7
// baseline (227.144 us; speedup 1.0000x reference)
//
#include <hip/hip_runtime.h>
#include <stdint.h>

// L2 1-NN, B=4096 x[B,256] vs N=32768 P[N,256] fp32.
// Round 7: barrier-free register-streaming screen. A-panel in VGPRs (K=256),
// B fragments loaded global->VGPR in MFMA layout (no LDS, no s_barrier, no
// hand vmcnt) — the compiler's per-use waitcnt scheduling pipelines it.
// 64-col-group u32 blockmin + fp32 margin rescore (unchanged, proven r2-r6).
// argmin_j (psq[j] - 2 x.p_j); x_sq drops out. Candidate set
// {64-col groups with approx groupmin <= approx_min + MARGIN} provably
// contains the exact argmin (MARGIN = 2.0 >= 2*max bf16 screening error).

#define NB 4096
#define NP 32768
#define ND 256
#define NG 512             // N / 64 column groups
#define MARGIN 2.0f

typedef __attribute__((ext_vector_type(8))) __bf16 bf16x8;
typedef __attribute__((ext_vector_type(4))) __bf16 bf16x4;
typedef __attribute__((ext_vector_type(4))) float f32x4;

// ---- workspace layout (bytes) ----
static constexpr size_t OFF_PSQ = 0;                               // 32768 f32
static constexpr size_t OFF_XB  = 131072;                          // 4096x256 bf16
static constexpr size_t OFF_PB  = OFF_XB + (size_t)NB * ND * 2;    // 32768x256 bf16
static constexpr size_t OFF_BM  = OFF_PB + (size_t)NP * ND * 2;    // 4096x512 u32
static constexpr size_t WS_NEED = OFF_BM + (size_t)NB * NG * 4;    // 27,394,048

__device__ __forceinline__ unsigned fkey(float f) {
    unsigned u = __float_as_uint(f);
    return (u & 0x80000000u) ? ~u : (u | 0x80000000u);
}
__device__ __forceinline__ float fkey_inv(unsigned u) {
    unsigned o = (u & 0x80000000u) ? (u & 0x7FFFFFFFu) : ~u;
    return __uint_as_float(o);
}
__device__ __forceinline__ unsigned long long umin64(unsigned long long a,
                                                     unsigned long long b) {
    return a < b ? a : b;
}
__device__ __forceinline__ unsigned umin32(unsigned a, unsigned b) {
    return a < b ? a : b;
}

// ------------------------------------------------- prep: bf16 convert + psq
__global__ void prep_kernel(const float* __restrict__ X, const float* __restrict__ P,
                            float* __restrict__ psq, __bf16* __restrict__ Xb,
                            __bf16* __restrict__ Pb) {
    int row  = blockIdx.x * 4 + (threadIdx.x >> 6);  // one wave per row
    int lane = threadIdx.x & 63;
    if (row < NP) {
        f32x4 v = ((const f32x4*)(P + (size_t)row * ND))[lane];
        bf16x4 b;
        b.x = (__bf16)v.x; b.y = (__bf16)v.y; b.z = (__bf16)v.z; b.w = (__bf16)v.w;
        ((bf16x4*)(Pb + (size_t)row * ND))[lane] = b;
        float s = v.x*v.x + v.y*v.y + v.z*v.z + v.w*v.w;
        #pragma unroll
        for (int off = 32; off > 0; off >>= 1) s += __shfl_down(s, off);
        if (lane == 0) psq[row] = s;
    } else {
        int r = row - NP;   // < NB
        f32x4 v = ((const f32x4*)(X + (size_t)r * ND))[lane];
        bf16x4 b;
        b.x = (__bf16)v.x; b.y = (__bf16)v.y; b.z = (__bf16)v.z; b.w = (__bf16)v.w;
        ((bf16x4*)(Xb + (size_t)r * ND))[lane] = b;
    }
}

// ---------------- register-streaming screen: no LDS, no barriers ------------
// 512 blocks = 16 row-blocks x 32 col-splits; bid = rowblk*32 + split so the
// 16 blocks sharing a split's 512KB B-panel all map to XCD split%8 (L2-local).
// 4 waves/block; wave = 64 rows x 1024-col sweep = 16 tiles of 64 cols.
// Per 32-k step: 4 global_load_dwordx4 (B frags, MFMA lane layout: lane l
// holds P[col = base + (l&15)][k = kq*32 + (l>>4)*8 .. +8]) + 16 MFMA.
// bv[2][4] double-buffer, all indices compile-time (rule #20).
__global__ __launch_bounds__(256, 2)
void nn_stream_kernel(const __bf16* __restrict__ Xb, const __bf16* __restrict__ Pb,
                      const float* __restrict__ psq,
                      unsigned* __restrict__ blockmin) {
    const int tid  = threadIdx.x;
    const int lane = tid & 63;
    const int wave = tid >> 6;
    const int bid    = blockIdx.x;
    const int rowblk = bid >> 5;        // 0..15
    const int split  = bid & 31;        // 0..31 -> XCD = split%8
    const int bm     = rowblk * 256 + wave * 64;
    const int colb0  = split * 1024;
    const int fr = lane & 15, kg = lane >> 4;

    // ---- A panel in registers: 64 rows x 256 k (128 VGPR) ----
    bf16x8 a[4][8];
    #pragma unroll
    for (int mi = 0; mi < 4; ++mi)
        #pragma unroll
        for (int kq = 0; kq < 8; ++kq)
            a[mi][kq] = *(const bf16x8*)(Xb +
                (size_t)(bm + mi * 16 + fr) * ND + kq * 32 + kg * 8);

    f32x4 acc[4][4];
    #pragma unroll
    for (int i = 0; i < 4; ++i)
        #pragma unroll
        for (int j = 0; j < 4; ++j) acc[i][j] = (f32x4){0.f, 0.f, 0.f, 0.f};

    // per-lane B base: col = colb0 + fr, k = kg*8
    const __bf16* pbase = Pb + (size_t)(colb0 + fr) * ND + kg * 8;

    bf16x8 bv[2][4];
    #pragma unroll
    for (int ni = 0; ni < 4; ++ni)
        bv[0][ni] = *(const bf16x8*)(pbase + (size_t)(ni * 16) * ND);

    #pragma unroll 1
    for (int t = 0; t < 16; ++t) {
        // psq for this tile's 64 cols (compiler hoists over the MFMA stream)
        float cq[4];
        #pragma unroll
        for (int ni = 0; ni < 4; ++ni)
            cq[ni] = psq[colb0 + t * 64 + ni * 16 + fr];

        #pragma unroll
        for (int kq = 0; kq < 8; ++kq) {
            const int cur = kq & 1, nxt = cur ^ 1;
            if (kq < 7) {
                #pragma unroll
                for (int ni = 0; ni < 4; ++ni)
                    bv[nxt][ni] = *(const bf16x8*)(pbase +
                        (size_t)(t * 64 + ni * 16) * ND + (kq + 1) * 32);
            } else {
                const int t2 = (t + 1) & 15;   // wrap: harmless dead prefetch
                #pragma unroll
                for (int ni = 0; ni < 4; ++ni)
                    bv[nxt][ni] = *(const bf16x8*)(pbase +
                        (size_t)(t2 * 64 + ni * 16) * ND);
            }
            #pragma unroll
            for (int mi = 0; mi < 4; ++mi)
                #pragma unroll
                for (int ni = 0; ni < 4; ++ni)
                    acc[mi][ni] = __builtin_amdgcn_mfma_f32_16x16x32_bf16(
                        a[mi][kq], bv[cur][ni], acc[mi][ni], 0, 0, 0);
        }

        // ---- per-tile epilogue: min over the tile's 64 cols, store key ----
        const int g = split * 16 + t;
        #pragma unroll
        for (int mi = 0; mi < 4; ++mi) {
            #pragma unroll
            for (int r = 0; r < 4; ++r) {
                float d = fmaf(-2.f, acc[mi][0][r], cq[0]);
                #pragma unroll
                for (int ni = 1; ni < 4; ++ni)
                    d = fminf(d, fmaf(-2.f, acc[mi][ni][r], cq[ni]));
                #pragma unroll
                for (int m = 1; m < 16; m <<= 1)
                    d = fminf(d, __shfl_xor(d, m));
                if (fr == 0)
                    blockmin[(size_t)(bm + mi * 16 + kg * 4 + r) * NG + g] =
                        fkey(d);
            }
        }
        #pragma unroll
        for (int i = 0; i < 4; ++i)
            #pragma unroll
            for (int j = 0; j < 4; ++j)
                acc[i][j] = (f32x4){0.f, 0.f, 0.f, 0.f};
    }
}

// ------------- per-row: approx min -> candidate 64-col groups -> fp32 rescore
__global__ __launch_bounds__(256)
void rescore_kernel(const float* __restrict__ X, const float* __restrict__ P,
                    const float* __restrict__ psq,
                    const unsigned* __restrict__ blockmin,
                    float* __restrict__ out) {
    __shared__ float Xs[256];
    __shared__ float part[256];
    __shared__ unsigned keymin[256];
    __shared__ unsigned short cand[NG];
    __shared__ int cnt;
    __shared__ unsigned bcol_s;

    const int row = blockIdx.x;
    const int tid = threadIdx.x;
    const unsigned* bmr = blockmin + (size_t)row * NG;

    unsigned k0 = bmr[tid], k1 = bmr[tid + 256];
    if (tid < 64)
        ((f32x4*)Xs)[tid] = ((const f32x4*)(X + (size_t)row * ND))[tid];
    if (tid == 0) cnt = 0;
    keymin[tid] = umin32(k0, k1);
    __syncthreads();
    #pragma unroll
    for (int s = 128; s > 0; s >>= 1) {
        if (tid < s) keymin[tid] = umin32(keymin[tid], keymin[tid + s]);
        __syncthreads();
    }
    unsigned thr = fkey(fkey_inv(keymin[0]) + MARGIN);
    if (k0 <= thr) cand[atomicAdd(&cnt, 1)] = (unsigned short)tid;
    if (k1 <= thr) cand[atomicAdd(&cnt, 1)] = (unsigned short)(tid + 256);
    __syncthreads();

    const int n     = cnt;
    const int ct    = tid & 63;     // col within group
    const int cpart = tid >> 6;     // k-quarter (64 dims)
    unsigned long long best = 0xFFFFFFFFFFFFFFFFull;
    for (int c = 0; c < n; ++c) {
        int g = cand[c];
        int col = g * 64 + ct;
        const f32x4* p4 = (const f32x4*)(P + (size_t)col * ND + cpart * 64);
        const f32x4* x4 = (const f32x4*)(Xs + cpart * 64);
        float s = 0.f;
        #pragma unroll
        for (int i = 0; i < 16; ++i) {
            f32x4 pv = p4[i], xv = x4[i];
            s = fmaf(xv.x, pv.x, s); s = fmaf(xv.y, pv.y, s);
            s = fmaf(xv.z, pv.z, s); s = fmaf(xv.w, pv.w, s);
        }
        part[tid] = s;
        __syncthreads();
        if (tid < 64) {
            int col2 = g * 64 + tid;
            float tot = part[tid] + part[tid + 64] + part[tid + 128] + part[tid + 192];
            float d = fmaf(-2.f, tot, psq[col2]);
            best = umin64(best, ((unsigned long long)fkey(d) << 32) |
                                (unsigned long long)col2);
        }
        __syncthreads();
    }
    if (tid < 64) {
        #pragma unroll
        for (int m = 1; m < 64; m <<= 1)
            best = umin64(best, __shfl_xor(best, m));
        if (tid == 0) bcol_s = (unsigned)(best & 0xFFFFFFFFull);
    }
    __syncthreads();
    unsigned bc = bcol_s;
    if (tid < 64)
        ((f32x4*)(out + (size_t)row * ND))[tid] =
            ((const f32x4*)(P + (size_t)bc * ND))[tid];
}

// ======================= fallback: exact fp32 path (small ws) ===============
#define BM1 128
#define BN1 128
#define BK1 32
#define LDA1 132

__global__ void psq_init_kernel(const float* __restrict__ P, float* __restrict__ psq,
                                unsigned long long* __restrict__ minpack) {
    int row  = blockIdx.x * 4 + (threadIdx.x >> 6);
    int lane = threadIdx.x & 63;
    float4 p4 = ((const float4*)(P + (size_t)row * ND))[lane];
    float s = p4.x*p4.x + p4.y*p4.y + p4.z*p4.z + p4.w*p4.w;
    #pragma unroll
    for (int off = 32; off > 0; off >>= 1) s += __shfl_down(s, off);
    if (lane == 0) psq[row] = s;
    int gid = blockIdx.x * blockDim.x + threadIdx.x;
    if (gid < NB) minpack[gid] = 0xFFFFFFFFFFFFFFFFull;
}

__global__ __launch_bounds__(256, 2)
void nn_main_kernel(const float* __restrict__ X, const float* __restrict__ P,
                    const float* __restrict__ psq,
                    unsigned long long* __restrict__ minpack) {
    __shared__ __align__(16) char smem_raw[2 * BK1 * LDA1 * 4];
    float (*As)[LDA1] = (float (*)[LDA1])smem_raw;
    float (*Bs)[LDA1] = (float (*)[LDA1])(smem_raw + BK1 * LDA1 * 4);
    const int bm  = blockIdx.y * BM1;
    const int bn  = blockIdx.x * BN1;
    const int tid = threadIdx.x;
    const int tx  = tid & 15;
    const int ty  = tid >> 4;
    float acc[8][8];
    #pragma unroll
    for (int i = 0; i < 8; ++i)
        #pragma unroll
        for (int j = 0; j < 8; ++j) acc[i][j] = 0.f;
    const int lrow = tid >> 3;
    const int lk   = (tid & 7) * 4;
    for (int k0 = 0; k0 < ND; k0 += BK1) {
        #pragma unroll
        for (int p = 0; p < 4; ++p) {
            int r = p * 32 + lrow;
            float4 a = *(const float4*)(X + (size_t)(bm + r) * ND + k0 + lk);
            As[lk+0][r] = a.x; As[lk+1][r] = a.y; As[lk+2][r] = a.z; As[lk+3][r] = a.w;
            float4 b = *(const float4*)(P + (size_t)(bn + r) * ND + k0 + lk);
            Bs[lk+0][r] = b.x; Bs[lk+1][r] = b.y; Bs[lk+2][r] = b.z; Bs[lk+3][r] = b.w;
        }
        __syncthreads();
        #pragma unroll 4
        for (int k = 0; k < BK1; ++k) {
            float4 a0 = *(const float4*)&As[k][ty*8];
            float4 a1 = *(const float4*)&As[k][ty*8 + 4];
            float4 b0 = *(const float4*)&Bs[k][tx*4];
            float4 b1 = *(const float4*)&Bs[k][64 + tx*4];
            float av[8] = {a0.x,a0.y,a0.z,a0.w,a1.x,a1.y,a1.z,a1.w};
            float bv[8] = {b0.x,b0.y,b0.z,b0.w,b1.x,b1.y,b1.z,b1.w};
            #pragma unroll
            for (int i = 0; i < 8; ++i)
                #pragma unroll
                for (int j = 0; j < 8; ++j)
                    acc[i][j] = fmaf(av[i], bv[j], acc[i][j]);
        }
        __syncthreads();
    }
    unsigned long long (*red)[16] = (unsigned long long (*)[16])smem_raw;
    float cj[8];
    int   jglob[8];
    #pragma unroll
    for (int j = 0; j < 8; ++j) {
        int c = (j < 4) ? (tx*4 + j) : (64 + tx*4 + (j - 4));
        jglob[j] = bn + c;
        cj[j]    = psq[bn + c];
    }
    #pragma unroll
    for (int i = 0; i < 8; ++i) {
        float best = 0.f; unsigned bidx = 0u; bool first = true;
        #pragma unroll
        for (int j = 0; j < 8; ++j) {
            float s = fmaf(-2.f, acc[i][j], cj[j]);
            if (first || s < best) { best = s; bidx = (unsigned)jglob[j]; first = false; }
        }
        unsigned u = fkey(best);
        red[ty*8 + i][tx] = ((unsigned long long)u << 32) | (unsigned long long)bidx;
    }
    __syncthreads();
    if (tid < BM1) {
        unsigned long long m = red[tid][0];
        #pragma unroll
        for (int t = 1; t < 16; ++t) m = umin64(m, red[tid][t]);
        atomicMin(&minpack[bm + tid], m);
    }
}

__global__ void gather_kernel(const float* __restrict__ P,
                              const unsigned long long* __restrict__ minpack,
                              float* __restrict__ out) {
    int row = blockIdx.x;
    unsigned idx = (unsigned)(minpack[row] & 0xFFFFFFFFull);
    int lane = threadIdx.x;
    ((float4*)(out + (size_t)row * ND))[lane] =
        ((const float4*)(P + (size_t)idx * ND))[lane];
}

// ------------------------------------------------------------------- launch
extern "C" void kernel_launch(void* const* d_in, const int* in_sizes, int n_in,
                              void* d_out, int out_size, void* d_ws, size_t ws_size,
                              hipStream_t stream) {
    const float* X = (const float*)d_in[0];
    const float* P = (const float*)d_in[1];
    float* out = (float*)d_out;
    char* w = (char*)d_ws;

    if (ws_size >= WS_NEED) {
        float* psq = (float*)(w + OFF_PSQ);
        __bf16* Xb = (__bf16*)(w + OFF_XB);
        __bf16* Pb = (__bf16*)(w + OFF_PB);
        unsigned* blockmin = (unsigned*)(w + OFF_BM);

        prep_kernel<<<(NP + NB) / 4, 256, 0, stream>>>(X, P, psq, Xb, Pb);
        nn_stream_kernel<<<512, 256, 0, stream>>>(Xb, Pb, psq, blockmin);
        rescore_kernel<<<NB, 256, 0, stream>>>(X, P, psq, blockmin, out);
    } else {
        float* psq = (float*)w;
        unsigned long long* minpack = (unsigned long long*)(w + (size_t)NP * 4);
        psq_init_kernel<<<NP / 4, 256, 0, stream>>>(P, psq, minpack);
        dim3 grid(NP / BN1, NB / BM1);
        nn_main_kernel<<<grid, dim3(256), 0, stream>>>(X, P, psq, minpack);
        gather_kernel<<<NB, 64, 0, stream>>>(P, minpack, out);
    }
}

// Round 9
// 226.948 us; speedup vs baseline: 1.0009x; 1.0009x over previous
//
#include <hip/hip_runtime.h>
#include <stdint.h>

// L2 1-NN, B=4096 x[B,256] vs N=32768 P[N,256] fp32.
// Round 9: R8's pipeline with the race fixed. Invariant restored:
//   VMCNT(own) -> s_barrier -> ds_read   (barrier publishes ALL waves' staging)
// Body: VMCNT(6); barrier; read(t+1)->bv[nxt]; stage(t+5); MFMA(t) on bv[cur].
// Read latency + stage issue hide under the MFMA cluster. Ring 6x16KB pieces,
// A in VGPRs (K=256), psq+blockmin table in LDS (vmcnt stays pure), one flush
// per block. Rescore: one wave per row, barrier-free.
// argmin_j (psq[j] - 2 x.p_j); x_sq drops out. Candidate set
// {64-col groups with groupmin <= approx_min + MARGIN} provably contains the
// exact argmin (MARGIN = 2.0 >= worst-case 2*bf16 screening error).

#define NB 4096
#define NP 32768
#define ND 256
#define NG 512             // N / 64 column groups
#define MARGIN 2.0f
#define NSPLIT 8
#define CPB 4096           // cols per block (NP / NSPLIT)

typedef __attribute__((ext_vector_type(8))) __bf16 bf16x8;
typedef __attribute__((ext_vector_type(4))) __bf16 bf16x4;
typedef __attribute__((ext_vector_type(4))) float f32x4;

// ---- workspace layout (bytes) ----
static constexpr size_t OFF_PSQ = 0;                               // 32768 f32
static constexpr size_t OFF_XB  = 131072;                          // 4096x256 bf16
static constexpr size_t OFF_PB  = OFF_XB + (size_t)NB * ND * 2;    // 32768x256 bf16
static constexpr size_t OFF_BM  = OFF_PB + (size_t)NP * ND * 2;    // 4096x512 u32
static constexpr size_t WS_NEED = OFF_BM + (size_t)NB * NG * 4;    // 27,394,048

#define VMCNT(n) asm volatile("s_waitcnt vmcnt(" #n ")" ::: "memory")
#define LGKM0()  asm volatile("s_waitcnt lgkmcnt(0)" ::: "memory")

__device__ __forceinline__ void gload_lds16(const void* g, void* l) {
    __builtin_amdgcn_global_load_lds(
        (const __attribute__((address_space(1))) uint32_t*)g,
        (__attribute__((address_space(3))) uint32_t*)l, 16, 0, 0);
}
__device__ __forceinline__ unsigned fkey(float f) {
    unsigned u = __float_as_uint(f);
    return (u & 0x80000000u) ? ~u : (u | 0x80000000u);
}
__device__ __forceinline__ float fkey_inv(unsigned u) {
    unsigned o = (u & 0x80000000u) ? (u & 0x7FFFFFFFu) : ~u;
    return __uint_as_float(o);
}
__device__ __forceinline__ unsigned long long umin64(unsigned long long a,
                                                     unsigned long long b) {
    return a < b ? a : b;
}
__device__ __forceinline__ unsigned umin32(unsigned a, unsigned b) {
    return a < b ? a : b;
}

// ------------------------------------------------- prep: bf16 convert + psq
__global__ void prep_kernel(const float* __restrict__ X, const float* __restrict__ P,
                            float* __restrict__ psq, __bf16* __restrict__ Xb,
                            __bf16* __restrict__ Pb) {
    int row  = blockIdx.x * 4 + (threadIdx.x >> 6);  // one wave per row
    int lane = threadIdx.x & 63;
    if (row < NP) {
        f32x4 v = ((const f32x4*)(P + (size_t)row * ND))[lane];
        bf16x4 b;
        b.x = (__bf16)v.x; b.y = (__bf16)v.y; b.z = (__bf16)v.z; b.w = (__bf16)v.w;
        ((bf16x4*)(Pb + (size_t)row * ND))[lane] = b;
        float s = v.x*v.x + v.y*v.y + v.z*v.z + v.w*v.w;
        #pragma unroll
        for (int off = 32; off > 0; off >>= 1) s += __shfl_down(s, off);
        if (lane == 0) psq[row] = s;
    } else {
        int r = row - NP;   // < NB
        f32x4 v = ((const f32x4*)(X + (size_t)r * ND))[lane];
        bf16x4 b;
        b.x = (__bf16)v.x; b.y = (__bf16)v.y; b.z = (__bf16)v.z; b.w = (__bf16)v.w;
        ((bf16x4*)(Xb + (size_t)r * ND))[lane] = b;
    }
}

// -------------------- pipelined N-sweep screen (race-fixed) -----------------
// 512 thr = 8 waves (wm 0..1 x wn 0..3). Block: 128 rows x 4096-col sweep =
// 128 pieces (piece p: n-tile p>>3, 32-k slab p&7; 256 cols x 32 k = 16KB).
// Ring 6 x 16KB, slot = p % 6; stage lead 5 => 3 pieces in flight at the wait.
// Body t: VMCNT(6) [drains own stage(t+1)]; s_barrier [ALL waves drained];
// sched_barrier; ds_read slot(t+1)->bv[nxt]; stage(t+5); 16 MFMA on bv[cur].
// WAR: stage(t+5) writes slot (t-1)%6; its readers (body t-2) finished before
// their MFMA (body t-1) which precedes barrier(t); stage is after barrier(t).
// Grid = 256 blocks (1/CU); bid&7 = split -> XCD-local 2MB B-panel.
__global__ __launch_bounds__(512, 2)
void nn_pipe_kernel(const __bf16* __restrict__ Xb, const __bf16* __restrict__ Pb,
                    const float* __restrict__ psq,
                    unsigned* __restrict__ blockmin) {
    __shared__ __align__(16) char smem[147456];
    char*     ring    = smem;                        // 6 x 16KB
    float*    psq_lds = (float*)(smem + 98304);      // 4096 f32 (16KB)
    unsigned* tbl     = (unsigned*)(smem + 114688);  // [128 rows][64 groups]

    const int tid  = threadIdx.x;
    const int lane = tid & 63;
    const int wave = tid >> 6;
    const int wm = wave >> 2, wn = wave & 3;
    const int bid    = blockIdx.x;
    const int nsplit = bid & 7;
    const int mblk   = bid >> 3;
    const int bm     = mblk * 128;
    const int Nb     = nsplit * CPB;
    const int fr = lane & 15, kg = lane >> 4;
    const int wbase16 = (tid & ~63) * 16;

    // ---- A in registers: wave's 64 rows x full K=256 ----
    bf16x8 a[4][8];
    #pragma unroll
    for (int mi = 0; mi < 4; ++mi)
        #pragma unroll
        for (int qq = 0; qq < 8; ++qq)
            a[mi][qq] = *(const bf16x8*)(Xb +
                (size_t)(bm + wm * 64 + mi * 16 + fr) * ND + qq * 32 + kg * 8);

    f32x4 acc[4][4];
    #pragma unroll
    for (int i = 0; i < 4; ++i)
        #pragma unroll
        for (int j = 0; j < 4; ++j) acc[i][j] = (f32x4){0.f, 0.f, 0.f, 0.f};

    auto stage = [&](int p) {
        char* dst = ring + (size_t)(p % 6) * 16384;
        const int colb = Nb + (p >> 3) * 256;
        const int kq   = p & 7;
        #pragma unroll
        for (int i = 0; i < 2; ++i) {
            const int c = i * 512 + tid;          // chunk 0..1023
            const int fn = c >> 6;
            const int l  = c & 63;
            gload_lds16(Pb + (size_t)(colb + fn * 16 + (l & 15)) * ND +
                            kq * 32 + (l >> 4) * 8,
                        dst + i * 8192 + wbase16);
        }
    };

    bf16x8 bv[2][4];

    // ---- prologue: psq first (drains earliest), then pieces 0..4 ----
    gload_lds16((const char*)(psq + Nb) + (size_t)tid * 16,
                (char*)psq_lds + wbase16);
    gload_lds16((const char*)(psq + Nb) + 8192 + (size_t)tid * 16,
                (char*)psq_lds + 8192 + wbase16);
    stage(0); stage(1); stage(2); stage(3); stage(4);
    VMCNT(8);                                 // drains psq + piece 0 (own)
    __builtin_amdgcn_s_barrier();             // all waves' piece 0 landed
    __builtin_amdgcn_sched_barrier(0);
    #pragma unroll
    for (int ni = 0; ni < 4; ++ni)
        bv[0][ni] = *(const bf16x8*)(ring +
                     (size_t)((wn * 4 + ni) * 64 + lane) * 16);

    // epilogue for tile nt: per-row min over wave's 64 cols -> tbl (LDS only)
    auto epi = [&](int nt) {
        float cq[4];
        #pragma unroll
        for (int ni = 0; ni < 4; ++ni)
            cq[ni] = psq_lds[nt * 256 + wn * 64 + ni * 16 + fr];
        #pragma unroll
        for (int mi = 0; mi < 4; ++mi) {
            #pragma unroll
            for (int r = 0; r < 4; ++r) {
                float d = fmaf(-2.f, acc[mi][0][r], cq[0]);
                #pragma unroll
                for (int ni = 1; ni < 4; ++ni)
                    d = fminf(d, fmaf(-2.f, acc[mi][ni][r], cq[ni]));
                #pragma unroll
                for (int m = 1; m < 16; m <<= 1)
                    d = fminf(d, __shfl_xor(d, m));
                if (fr == 0)
                    tbl[(wm * 64 + mi * 16 + kg * 4 + r) * 64 + (nt * 4 + wn)] =
                        fkey(d);
            }
        }
        #pragma unroll
        for (int i = 0; i < 4; ++i)
            #pragma unroll
            for (int j = 0; j < 4; ++j)
                acc[i][j] = (f32x4){0.f, 0.f, 0.f, 0.f};
    };

    // ---- main loop: tiles 0..14 (bodies t=0..119, uniform) ----
    #pragma unroll 1
    for (int nt = 0; nt < 15; ++nt) {
        #pragma unroll
        for (int q = 0; q < 8; ++q) {
            const int cur = q & 1, nxt = cur ^ 1;
            const int t = nt * 8 + q;
            VMCNT(6);                          // own stage(t+1) drained
            __builtin_amdgcn_s_barrier();      // ALL waves' stage(t+1) drained
            __builtin_amdgcn_sched_barrier(0);
            const char* pc = ring + (size_t)(((t + 1) % 6)) * 16384;
            #pragma unroll
            for (int ni = 0; ni < 4; ++ni)
                bv[nxt][ni] = *(const bf16x8*)(pc +
                    (size_t)((wn * 4 + ni) * 64 + lane) * 16);
            stage(t + 5);                      // <= 124 in main loop
            __builtin_amdgcn_s_setprio(1);
            #pragma unroll
            for (int mi = 0; mi < 4; ++mi)
                #pragma unroll
                for (int ni = 0; ni < 4; ++ni)
                    acc[mi][ni] = __builtin_amdgcn_mfma_f32_16x16x32_bf16(
                        a[mi][q], bv[cur][ni], acc[mi][ni], 0, 0, 0);
            __builtin_amdgcn_s_setprio(0);
            if (q == 7) epi(nt);
        }
    }
    // ---- tail tile 15 (t=120..127): staging winds down ----
    #pragma unroll
    for (int q = 0; q < 8; ++q) {
        const int cur = q & 1, nxt = cur ^ 1;
        const int t = 120 + q;
        if (q <= 3)      { VMCNT(6); }
        else if (q == 4) { VMCNT(4); }
        else if (q == 5) { VMCNT(2); }
        else if (q == 6) { VMCNT(0); }
        if (q < 7) {
            __builtin_amdgcn_s_barrier();
            __builtin_amdgcn_sched_barrier(0);
            const char* pc = ring + (size_t)(((t + 1) % 6)) * 16384;
            #pragma unroll
            for (int ni = 0; ni < 4; ++ni)
                bv[nxt][ni] = *(const bf16x8*)(pc +
                    (size_t)((wn * 4 + ni) * 64 + lane) * 16);
            if (q < 3) stage(t + 5);           // pieces 125..127
        }
        __builtin_amdgcn_s_setprio(1);
        #pragma unroll
        for (int mi = 0; mi < 4; ++mi)
            #pragma unroll
            for (int ni = 0; ni < 4; ++ni)
                acc[mi][ni] = __builtin_amdgcn_mfma_f32_16x16x32_bf16(
                    a[mi][q], bv[cur][ni], acc[mi][ni], 0, 0, 0);
        __builtin_amdgcn_s_setprio(0);
        if (q == 7) epi(15);
    }

    // ---- flush blockmin table: 8192 u32, coalesced ----
    __syncthreads();
    const int rl = tid >> 2;             // row_local 0..127
    const int gb = (tid & 3) * 16;       // group base within row
    #pragma unroll
    for (int j = 0; j < 4; ++j) {
        *(uint4*)&blockmin[(size_t)(bm + rl) * NG + nsplit * 64 + gb + j * 4] =
            *(const uint4*)&tbl[rl * 64 + gb + j * 4];
    }
}

// ---------------- rescore: one wave per row, barrier-free -------------------
// Per row: 8 keys/lane -> wave-min -> threshold -> candidate list via LDS
// atomics (same-wave in-order DS, no barrier) -> per candidate group: lane =
// col, full 256-d fp32 dot vs LDS-cached x -> u64 key min -> shfl -> gather.
__global__ __launch_bounds__(512, 2)
void rescore_wave_kernel(const float* __restrict__ X, const float* __restrict__ P,
                         const float* __restrict__ psq,
                         const unsigned* __restrict__ blockmin,
                         float* __restrict__ out) {
    __shared__ float Xs[8][256];
    __shared__ unsigned short wcand[8][512];
    __shared__ int wcnt[8];

    const int tid = threadIdx.x, lane = tid & 63, wv = tid >> 6;
    const int row = blockIdx.x * 8 + wv;

    ((f32x4*)Xs[wv])[lane] = ((const f32x4*)(X + (size_t)row * ND))[lane];
    if (lane == 0) wcnt[wv] = 0;

    const unsigned* bmr = blockmin + (size_t)row * NG;
    uint4 ka = ((const uint4*)bmr)[lane * 2];
    uint4 kb = ((const uint4*)bmr)[lane * 2 + 1];
    unsigned km = umin32(umin32(umin32(ka.x, ka.y), umin32(ka.z, ka.w)),
                         umin32(umin32(kb.x, kb.y), umin32(kb.z, kb.w)));
    #pragma unroll
    for (int m = 1; m < 64; m <<= 1) km = umin32(km, __shfl_xor(km, m));
    const unsigned thr = fkey(fkey_inv(km) + MARGIN);

    const unsigned k8[8] = {ka.x, ka.y, ka.z, ka.w, kb.x, kb.y, kb.z, kb.w};
    #pragma unroll
    for (int i = 0; i < 8; ++i)
        if (k8[i] <= thr)
            wcand[wv][atomicAdd(&wcnt[wv], 1)] = (unsigned short)(lane * 8 + i);
    LGKM0();                             // same-wave DS ops complete, in order
    const int n = wcnt[wv];

    unsigned long long best = 0xFFFFFFFFFFFFFFFFull;
    const f32x4* x4 = (const f32x4*)Xs[wv];
    for (int c = 0; c < n; ++c) {
        const int col = (int)wcand[wv][c] * 64 + lane;
        const f32x4* p4 = (const f32x4*)(P + (size_t)col * ND);
        float s = 0.f;
        #pragma unroll 16
        for (int i = 0; i < 64; ++i) {
            f32x4 pv = p4[i], xv = x4[i];
            s = fmaf(xv.x, pv.x, s); s = fmaf(xv.y, pv.y, s);
            s = fmaf(xv.z, pv.z, s); s = fmaf(xv.w, pv.w, s);
        }
        float d = fmaf(-2.f, s, psq[col]);
        best = umin64(best, ((unsigned long long)fkey(d) << 32) |
                            (unsigned long long)(unsigned)col);
    }
    #pragma unroll
    for (int m = 1; m < 64; m <<= 1)
        best = umin64(best, __shfl_xor(best, m));
    const unsigned bc = (unsigned)(best & 0xFFFFFFFFull);
    ((f32x4*)(out + (size_t)row * ND))[lane] =
        ((const f32x4*)(P + (size_t)bc * ND))[lane];
}

// ======================= fallback: exact fp32 path (small ws) ===============
#define BM1 128
#define BN1 128
#define BK1 32
#define LDA1 132

__global__ void psq_init_kernel(const float* __restrict__ P, float* __restrict__ psq,
                                unsigned long long* __restrict__ minpack) {
    int row  = blockIdx.x * 4 + (threadIdx.x >> 6);
    int lane = threadIdx.x & 63;
    float4 p4 = ((const float4*)(P + (size_t)row * ND))[lane];
    float s = p4.x*p4.x + p4.y*p4.y + p4.z*p4.z + p4.w*p4.w;
    #pragma unroll
    for (int off = 32; off > 0; off >>= 1) s += __shfl_down(s, off);
    if (lane == 0) psq[row] = s;
    int gid = blockIdx.x * blockDim.x + threadIdx.x;
    if (gid < NB) minpack[gid] = 0xFFFFFFFFFFFFFFFFull;
}

__global__ __launch_bounds__(256, 2)
void nn_main_kernel(const float* __restrict__ X, const float* __restrict__ P,
                    const float* __restrict__ psq,
                    unsigned long long* __restrict__ minpack) {
    __shared__ __align__(16) char smem_raw[2 * BK1 * LDA1 * 4];
    float (*As)[LDA1] = (float (*)[LDA1])smem_raw;
    float (*Bs)[LDA1] = (float (*)[LDA1])(smem_raw + BK1 * LDA1 * 4);
    const int bm  = blockIdx.y * BM1;
    const int bn  = blockIdx.x * BN1;
    const int tid = threadIdx.x;
    const int tx  = tid & 15;
    const int ty  = tid >> 4;
    float acc[8][8];
    #pragma unroll
    for (int i = 0; i < 8; ++i)
        #pragma unroll
        for (int j = 0; j < 8; ++j) acc[i][j] = 0.f;
    const int lrow = tid >> 3;
    const int lk   = (tid & 7) * 4;
    for (int k0 = 0; k0 < ND; k0 += BK1) {
        #pragma unroll
        for (int p = 0; p < 4; ++p) {
            int r = p * 32 + lrow;
            float4 aa = *(const float4*)(X + (size_t)(bm + r) * ND + k0 + lk);
            As[lk+0][r] = aa.x; As[lk+1][r] = aa.y; As[lk+2][r] = aa.z; As[lk+3][r] = aa.w;
            float4 bb = *(const float4*)(P + (size_t)(bn + r) * ND + k0 + lk);
            Bs[lk+0][r] = bb.x; Bs[lk+1][r] = bb.y; Bs[lk+2][r] = bb.z; Bs[lk+3][r] = bb.w;
        }
        __syncthreads();
        #pragma unroll 4
        for (int k = 0; k < BK1; ++k) {
            float4 a0 = *(const float4*)&As[k][ty*8];
            float4 a1 = *(const float4*)&As[k][ty*8 + 4];
            float4 b0 = *(const float4*)&Bs[k][tx*4];
            float4 b1 = *(const float4*)&Bs[k][64 + tx*4];
            float av[8] = {a0.x,a0.y,a0.z,a0.w,a1.x,a1.y,a1.z,a1.w};
            float bvv[8] = {b0.x,b0.y,b0.z,b0.w,b1.x,b1.y,b1.z,b1.w};
            #pragma unroll
            for (int i = 0; i < 8; ++i)
                #pragma unroll
                for (int j = 0; j < 8; ++j)
                    acc[i][j] = fmaf(av[i], bvv[j], acc[i][j]);
        }
        __syncthreads();
    }
    unsigned long long (*red)[16] = (unsigned long long (*)[16])smem_raw;
    float cj[8];
    int   jglob[8];
    #pragma unroll
    for (int j = 0; j < 8; ++j) {
        int c = (j < 4) ? (tx*4 + j) : (64 + tx*4 + (j - 4));
        jglob[j] = bn + c;
        cj[j]    = psq[bn + c];
    }
    #pragma unroll
    for (int i = 0; i < 8; ++i) {
        float bestv = 0.f; unsigned bidx = 0u; bool first = true;
        #pragma unroll
        for (int j = 0; j < 8; ++j) {
            float s = fmaf(-2.f, acc[i][j], cj[j]);
            if (first || s < bestv) { bestv = s; bidx = (unsigned)jglob[j]; first = false; }
        }
        unsigned u = fkey(bestv);
        red[ty*8 + i][tx] = ((unsigned long long)u << 32) | (unsigned long long)bidx;
    }
    __syncthreads();
    if (tid < BM1) {
        unsigned long long m = red[tid][0];
        #pragma unroll
        for (int t = 1; t < 16; ++t) m = umin64(m, red[tid][t]);
        atomicMin(&minpack[bm + tid], m);
    }
}

__global__ void gather_kernel(const float* __restrict__ P,
                              const unsigned long long* __restrict__ minpack,
                              float* __restrict__ out) {
    int row = blockIdx.x;
    unsigned idx = (unsigned)(minpack[row] & 0xFFFFFFFFull);
    int lane = threadIdx.x;
    ((float4*)(out + (size_t)row * ND))[lane] =
        ((const float4*)(P + (size_t)idx * ND))[lane];
}

// ------------------------------------------------------------------- launch
extern "C" void kernel_launch(void* const* d_in, const int* in_sizes, int n_in,
                              void* d_out, int out_size, void* d_ws, size_t ws_size,
                              hipStream_t stream) {
    const float* X = (const float*)d_in[0];
    const float* P = (const float*)d_in[1];
    float* out = (float*)d_out;
    char* w = (char*)d_ws;

    if (ws_size >= WS_NEED) {
        float* psq = (float*)(w + OFF_PSQ);
        __bf16* Xb = (__bf16*)(w + OFF_XB);
        __bf16* Pb = (__bf16*)(w + OFF_PB);
        unsigned* blockmin = (unsigned*)(w + OFF_BM);

        prep_kernel<<<(NP + NB) / 4, 256, 0, stream>>>(X, P, psq, Xb, Pb);
        nn_pipe_kernel<<<(NB / 128) * NSPLIT, 512, 0, stream>>>(Xb, Pb, psq,
                                                                blockmin);
        rescore_wave_kernel<<<NB / 8, 512, 0, stream>>>(X, P, psq, blockmin, out);
    } else {
        float* psq = (float*)w;
        unsigned long long* minpack = (unsigned long long*)(w + (size_t)NP * 4);
        psq_init_kernel<<<NP / 4, 256, 0, stream>>>(P, psq, minpack);
        dim3 grid(NP / BN1, NB / BM1);
        nn_main_kernel<<<grid, dim3(256), 0, stream>>>(X, P, psq, minpack);
        gather_kernel<<<NB, 64, 0, stream>>>(P, minpack, out);
    }
}

// Round 10
// 184.883 us; speedup vs baseline: 1.2286x; 1.2275x over previous
//
#include <hip/hip_runtime.h>
#include <stdint.h>

// L2 1-NN, B=4096 x[B,256] vs N=32768 P[N,256] fp32.
// Round 10: R9's pipeline, but A-tile in LDS (static, loaded once) instead of
// A-in-registers. R9's VGPR_Count=128 proved a[4][8] (128 VGPR) + bv + acc
// cannot be resident: the compiler was rematerializing A from global inside
// every body (exposed latency + corrupted vmcnt counting) -> 17.8% MfmaUtil.
// Now per-body av/bv are double-buffered from LDS (~130 VGPR, no remat).
// Ring 4x16KB (lead 3, VMCNT(2)); blockmin keys stored directly to global at
// each tile epilogue. Barrier discipline unchanged from R9 (race-free):
//   VMCNT(own) -> s_barrier -> ds_read.
// argmin_j (psq[j] - 2 x.p_j); x_sq drops out. Candidate set
// {64-col groups with groupmin <= approx_min + MARGIN} provably contains the
// exact argmin (MARGIN = 2.0 >= worst-case 2*bf16 screening error).

#define NB 4096
#define NP 32768
#define ND 256
#define NG 512             // N / 64 column groups
#define MARGIN 2.0f
#define NSPLIT 8
#define CPB 4096           // cols per block (NP / NSPLIT)

typedef __attribute__((ext_vector_type(8))) __bf16 bf16x8;
typedef __attribute__((ext_vector_type(4))) __bf16 bf16x4;
typedef __attribute__((ext_vector_type(4))) float f32x4;

// ---- workspace layout (bytes) ----
static constexpr size_t OFF_PSQ = 0;                               // 32768 f32
static constexpr size_t OFF_XB  = 131072;                          // 4096x256 bf16
static constexpr size_t OFF_PB  = OFF_XB + (size_t)NB * ND * 2;    // 32768x256 bf16
static constexpr size_t OFF_BM  = OFF_PB + (size_t)NP * ND * 2;    // 4096x512 u32
static constexpr size_t WS_NEED = OFF_BM + (size_t)NB * NG * 4;    // 27,394,048

#define VMCNT(n) asm volatile("s_waitcnt vmcnt(" #n ")" ::: "memory")
#define LGKM0()  asm volatile("s_waitcnt lgkmcnt(0)" ::: "memory")

__device__ __forceinline__ void gload_lds16(const void* g, void* l) {
    __builtin_amdgcn_global_load_lds(
        (const __attribute__((address_space(1))) uint32_t*)g,
        (__attribute__((address_space(3))) uint32_t*)l, 16, 0, 0);
}
__device__ __forceinline__ unsigned fkey(float f) {
    unsigned u = __float_as_uint(f);
    return (u & 0x80000000u) ? ~u : (u | 0x80000000u);
}
__device__ __forceinline__ float fkey_inv(unsigned u) {
    unsigned o = (u & 0x80000000u) ? (u & 0x7FFFFFFFu) : ~u;
    return __uint_as_float(o);
}
__device__ __forceinline__ unsigned long long umin64(unsigned long long a,
                                                     unsigned long long b) {
    return a < b ? a : b;
}
__device__ __forceinline__ unsigned umin32(unsigned a, unsigned b) {
    return a < b ? a : b;
}

// ------------------------------------------------- prep: bf16 convert + psq
__global__ void prep_kernel(const float* __restrict__ X, const float* __restrict__ P,
                            float* __restrict__ psq, __bf16* __restrict__ Xb,
                            __bf16* __restrict__ Pb) {
    int row  = blockIdx.x * 4 + (threadIdx.x >> 6);  // one wave per row
    int lane = threadIdx.x & 63;
    if (row < NP) {
        f32x4 v = ((const f32x4*)(P + (size_t)row * ND))[lane];
        bf16x4 b;
        b.x = (__bf16)v.x; b.y = (__bf16)v.y; b.z = (__bf16)v.z; b.w = (__bf16)v.w;
        ((bf16x4*)(Pb + (size_t)row * ND))[lane] = b;
        float s = v.x*v.x + v.y*v.y + v.z*v.z + v.w*v.w;
        #pragma unroll
        for (int off = 32; off > 0; off >>= 1) s += __shfl_down(s, off);
        if (lane == 0) psq[row] = s;
    } else {
        int r = row - NP;   // < NB
        f32x4 v = ((const f32x4*)(X + (size_t)r * ND))[lane];
        bf16x4 b;
        b.x = (__bf16)v.x; b.y = (__bf16)v.y; b.z = (__bf16)v.z; b.w = (__bf16)v.w;
        ((bf16x4*)(Xb + (size_t)r * ND))[lane] = b;
    }
}

// ------------------ N-sweep screen: A-tile in LDS, B ring-streamed ----------
// 512 thr = 8 waves (wm 0..1 x wn 0..3). Block: 128 rows x 4096-col sweep =
// 128 pieces (piece p: n-tile p>>3, 32-k slab p&7; 256 cols x 32 k = 16KB).
// LDS: ring 4x16KB | A 64KB (static: 128 rows x 256 k, lane-linear chunks
// ((q*8+fm)*64+lane)*16B) | psq 16KB.  av/bv double-buffered per body.
// Body t: VMCNT(2) [own stage(t+1) drained]; s_barrier [ALL waves drained];
// ds_read bv[nxt] slot (t+1)&3 + av[nxt] (q+1 frags, A static); stage(t+3);
// 16 MFMA on av[cur],bv[cur]; q==7: epilogue -> global stores (keys).
// WAR on slot (t+3)&3 = (t-1)&3: its ds_reads executed in body t-1 before
// barrier(t); the DMA write starts after barrier(t). Grid 256 (1 block/CU);
// bid&7 = split -> XCD-local 2MB B-panel.
__global__ __launch_bounds__(512, 2)
void nn_alds_kernel(const __bf16* __restrict__ Xb, const __bf16* __restrict__ Pb,
                    const float* __restrict__ psq,
                    unsigned* __restrict__ blockmin) {
    __shared__ __align__(16) char smem[147456];
    char*  ring    = smem;                        // 4 x 16KB
    char*  A_lds   = smem + 65536;                // 64KB
    float* psq_lds = (float*)(smem + 131072);     // 4096 f32 (16KB)

    const int tid  = threadIdx.x;
    const int lane = tid & 63;
    const int wave = tid >> 6;
    const int wm = wave >> 2, wn = wave & 3;
    const int bid    = blockIdx.x;
    const int nsplit = bid & 7;
    const int mblk   = bid >> 3;
    const int bm     = mblk * 128;
    const int Nb     = nsplit * CPB;
    const int fr = lane & 15, kg = lane >> 4;
    const int wbase16 = (tid & ~63) * 16;

    f32x4 acc[4][4];
    #pragma unroll
    for (int i = 0; i < 4; ++i)
        #pragma unroll
        for (int j = 0; j < 4; ++j) acc[i][j] = (f32x4){0.f, 0.f, 0.f, 0.f};

    auto stage = [&](int p) {
        char* dst = ring + (size_t)(p & 3) * 16384;
        const int colb = Nb + (p >> 3) * 256;
        const int kq   = p & 7;
        #pragma unroll
        for (int i = 0; i < 2; ++i) {
            const int c = i * 512 + tid;          // chunk 0..1023
            const int fn = c >> 6;
            const int l  = c & 63;
            gload_lds16(Pb + (size_t)(colb + fn * 16 + (l & 15)) * ND +
                            kq * 32 + (l >> 4) * 8,
                        dst + i * 8192 + wbase16);
        }
    };

    // ---- prologue: A-tile (8 issues), psq (2), pieces 0..2 (6) ----
    #pragma unroll
    for (int i = 0; i < 8; ++i) {
        const int c  = i * 512 + tid;             // chunk 0..4095
        const int q  = c >> 9;
        const int fm = (c >> 6) & 7;
        const int l  = c & 63;
        gload_lds16(Xb + (size_t)(bm + fm * 16 + (l & 15)) * ND +
                        q * 32 + (l >> 4) * 8,
                    A_lds + (size_t)(i * 512) * 16 + wbase16);
    }
    gload_lds16((const char*)(psq + Nb) + (size_t)tid * 16,
                (char*)psq_lds + wbase16);
    gload_lds16((const char*)(psq + Nb) + 8192 + (size_t)tid * 16,
                (char*)psq_lds + 8192 + wbase16);
    stage(0); stage(1); stage(2);
    VMCNT(4);                                 // A + psq + piece 0 drained (own)
    __builtin_amdgcn_s_barrier();             // ... for ALL waves
    __builtin_amdgcn_sched_barrier(0);

    bf16x8 av[2][4], bv[2][4];
    #pragma unroll
    for (int mi = 0; mi < 4; ++mi)
        av[0][mi] = *(const bf16x8*)(A_lds +
            (size_t)(((0 * 8) + (wm * 4 + mi)) * 64 + lane) * 16);
    #pragma unroll
    for (int ni = 0; ni < 4; ++ni)
        bv[0][ni] = *(const bf16x8*)(ring +
            (size_t)((wn * 4 + ni) * 64 + lane) * 16);

    // epilogue for tile nt: per-row min over wave's 64 cols -> global stores
    auto epi = [&](int nt) {
        float cq[4];
        #pragma unroll
        for (int ni = 0; ni < 4; ++ni)
            cq[ni] = psq_lds[nt * 256 + wn * 64 + ni * 16 + fr];
        const int g = nsplit * 64 + nt * 4 + wn;
        #pragma unroll
        for (int mi = 0; mi < 4; ++mi) {
            #pragma unroll
            for (int r = 0; r < 4; ++r) {
                float d = fmaf(-2.f, acc[mi][0][r], cq[0]);
                #pragma unroll
                for (int ni = 1; ni < 4; ++ni)
                    d = fminf(d, fmaf(-2.f, acc[mi][ni][r], cq[ni]));
                #pragma unroll
                for (int m = 1; m < 16; m <<= 1)
                    d = fminf(d, __shfl_xor(d, m));
                if (fr == 0)
                    blockmin[(size_t)(bm + wm * 64 + mi * 16 + kg * 4 + r) * NG
                             + g] = fkey(d);
            }
        }
        #pragma unroll
        for (int i = 0; i < 4; ++i)
            #pragma unroll
            for (int j = 0; j < 4; ++j)
                acc[i][j] = (f32x4){0.f, 0.f, 0.f, 0.f};
    };

    // ---- main loop: tiles 0..14 (bodies t=0..119, uniform) ----
    #pragma unroll 1
    for (int nt = 0; nt < 15; ++nt) {
        #pragma unroll
        for (int q = 0; q < 8; ++q) {
            const int cur = q & 1, nxt = cur ^ 1;
            const int t = nt * 8 + q;
            const int qn = (q + 1) & 7;
            VMCNT(2);                          // own stage(t+1) drained
            __builtin_amdgcn_s_barrier();      // ALL waves' stage(t+1) drained
            __builtin_amdgcn_sched_barrier(0);
            const char* pc = ring + (size_t)((t + 1) & 3) * 16384;
            #pragma unroll
            for (int ni = 0; ni < 4; ++ni)
                bv[nxt][ni] = *(const bf16x8*)(pc +
                    (size_t)((wn * 4 + ni) * 64 + lane) * 16);
            #pragma unroll
            for (int mi = 0; mi < 4; ++mi)
                av[nxt][mi] = *(const bf16x8*)(A_lds +
                    (size_t)((qn * 8 + wm * 4 + mi) * 64 + lane) * 16);
            stage(t + 3);                      // <= 122 in main loop
            __builtin_amdgcn_s_setprio(1);
            #pragma unroll
            for (int mi = 0; mi < 4; ++mi)
                #pragma unroll
                for (int ni = 0; ni < 4; ++ni)
                    acc[mi][ni] = __builtin_amdgcn_mfma_f32_16x16x32_bf16(
                        av[cur][mi], bv[cur][ni], acc[mi][ni], 0, 0, 0);
            __builtin_amdgcn_s_setprio(0);
            if (q == 7) epi(nt);
        }
    }
    // ---- tail tile 15 (t=120..127): staging winds down ----
    #pragma unroll
    for (int q = 0; q < 8; ++q) {
        const int cur = q & 1, nxt = cur ^ 1;
        const int t = 120 + q;
        const int qn = (q + 1) & 7;
        if (q <= 5) { VMCNT(2); }
        else        { VMCNT(0); }
        __builtin_amdgcn_s_barrier();
        __builtin_amdgcn_sched_barrier(0);
        if (q < 7) {
            const char* pc = ring + (size_t)((t + 1) & 3) * 16384;
            #pragma unroll
            for (int ni = 0; ni < 4; ++ni)
                bv[nxt][ni] = *(const bf16x8*)(pc +
                    (size_t)((wn * 4 + ni) * 64 + lane) * 16);
            #pragma unroll
            for (int mi = 0; mi < 4; ++mi)
                av[nxt][mi] = *(const bf16x8*)(A_lds +
                    (size_t)((qn * 8 + wm * 4 + mi) * 64 + lane) * 16);
            if (q <= 4) stage(t + 3);          // pieces 123..127
        }
        __builtin_amdgcn_s_setprio(1);
        #pragma unroll
        for (int mi = 0; mi < 4; ++mi)
            #pragma unroll
            for (int ni = 0; ni < 4; ++ni)
                acc[mi][ni] = __builtin_amdgcn_mfma_f32_16x16x32_bf16(
                    av[cur][mi], bv[cur][ni], acc[mi][ni], 0, 0, 0);
        __builtin_amdgcn_s_setprio(0);
        if (q == 7) epi(15);
    }
}

// ---------------- rescore: one wave per row, barrier-free -------------------
__global__ __launch_bounds__(512, 2)
void rescore_wave_kernel(const float* __restrict__ X, const float* __restrict__ P,
                         const float* __restrict__ psq,
                         const unsigned* __restrict__ blockmin,
                         float* __restrict__ out) {
    __shared__ float Xs[8][256];
    __shared__ unsigned short wcand[8][512];
    __shared__ int wcnt[8];

    const int tid = threadIdx.x, lane = tid & 63, wv = tid >> 6;
    const int row = blockIdx.x * 8 + wv;

    ((f32x4*)Xs[wv])[lane] = ((const f32x4*)(X + (size_t)row * ND))[lane];
    if (lane == 0) wcnt[wv] = 0;

    const unsigned* bmr = blockmin + (size_t)row * NG;
    uint4 ka = ((const uint4*)bmr)[lane * 2];
    uint4 kb = ((const uint4*)bmr)[lane * 2 + 1];
    unsigned km = umin32(umin32(umin32(ka.x, ka.y), umin32(ka.z, ka.w)),
                         umin32(umin32(kb.x, kb.y), umin32(kb.z, kb.w)));
    #pragma unroll
    for (int m = 1; m < 64; m <<= 1) km = umin32(km, __shfl_xor(km, m));
    const unsigned thr = fkey(fkey_inv(km) + MARGIN);

    const unsigned k8[8] = {ka.x, ka.y, ka.z, ka.w, kb.x, kb.y, kb.z, kb.w};
    #pragma unroll
    for (int i = 0; i < 8; ++i)
        if (k8[i] <= thr)
            wcand[wv][atomicAdd(&wcnt[wv], 1)] = (unsigned short)(lane * 8 + i);
    LGKM0();                             // same-wave DS ops complete, in order
    const int n = wcnt[wv];

    unsigned long long best = 0xFFFFFFFFFFFFFFFFull;
    const f32x4* x4 = (const f32x4*)Xs[wv];
    for (int c = 0; c < n; ++c) {
        const int col = (int)wcand[wv][c] * 64 + lane;
        const f32x4* p4 = (const f32x4*)(P + (size_t)col * ND);
        float s = 0.f;
        #pragma unroll 16
        for (int i = 0; i < 64; ++i) {
            f32x4 pv = p4[i], xv = x4[i];
            s = fmaf(xv.x, pv.x, s); s = fmaf(xv.y, pv.y, s);
            s = fmaf(xv.z, pv.z, s); s = fmaf(xv.w, pv.w, s);
        }
        float d = fmaf(-2.f, s, psq[col]);
        best = umin64(best, ((unsigned long long)fkey(d) << 32) |
                            (unsigned long long)(unsigned)col);
    }
    #pragma unroll
    for (int m = 1; m < 64; m <<= 1)
        best = umin64(best, __shfl_xor(best, m));
    const unsigned bc = (unsigned)(best & 0xFFFFFFFFull);
    ((f32x4*)(out + (size_t)row * ND))[lane] =
        ((const f32x4*)(P + (size_t)bc * ND))[lane];
}

// ======================= fallback: exact fp32 path (small ws) ===============
#define BM1 128
#define BN1 128
#define BK1 32
#define LDA1 132

__global__ void psq_init_kernel(const float* __restrict__ P, float* __restrict__ psq,
                                unsigned long long* __restrict__ minpack) {
    int row  = blockIdx.x * 4 + (threadIdx.x >> 6);
    int lane = threadIdx.x & 63;
    float4 p4 = ((const float4*)(P + (size_t)row * ND))[lane];
    float s = p4.x*p4.x + p4.y*p4.y + p4.z*p4.z + p4.w*p4.w;
    #pragma unroll
    for (int off = 32; off > 0; off >>= 1) s += __shfl_down(s, off);
    if (lane == 0) psq[row] = s;
    int gid = blockIdx.x * blockDim.x + threadIdx.x;
    if (gid < NB) minpack[gid] = 0xFFFFFFFFFFFFFFFFull;
}

__global__ __launch_bounds__(256, 2)
void nn_main_kernel(const float* __restrict__ X, const float* __restrict__ P,
                    const float* __restrict__ psq,
                    unsigned long long* __restrict__ minpack) {
    __shared__ __align__(16) char smem_raw[2 * BK1 * LDA1 * 4];
    float (*As)[LDA1] = (float (*)[LDA1])smem_raw;
    float (*Bs)[LDA1] = (float (*)[LDA1])(smem_raw + BK1 * LDA1 * 4);
    const int bm  = blockIdx.y * BM1;
    const int bn  = blockIdx.x * BN1;
    const int tid = threadIdx.x;
    const int tx  = tid & 15;
    const int ty  = tid >> 4;
    float acc[8][8];
    #pragma unroll
    for (int i = 0; i < 8; ++i)
        #pragma unroll
        for (int j = 0; j < 8; ++j) acc[i][j] = 0.f;
    const int lrow = tid >> 3;
    const int lk   = (tid & 7) * 4;
    for (int k0 = 0; k0 < ND; k0 += BK1) {
        #pragma unroll
        for (int p = 0; p < 4; ++p) {
            int r = p * 32 + lrow;
            float4 aa = *(const float4*)(X + (size_t)(bm + r) * ND + k0 + lk);
            As[lk+0][r] = aa.x; As[lk+1][r] = aa.y; As[lk+2][r] = aa.z; As[lk+3][r] = aa.w;
            float4 bb = *(const float4*)(P + (size_t)(bn + r) * ND + k0 + lk);
            Bs[lk+0][r] = bb.x; Bs[lk+1][r] = bb.y; Bs[lk+2][r] = bb.z; Bs[lk+3][r] = bb.w;
        }
        __syncthreads();
        #pragma unroll 4
        for (int k = 0; k < BK1; ++k) {
            float4 a0 = *(const float4*)&As[k][ty*8];
            float4 a1 = *(const float4*)&As[k][ty*8 + 4];
            float4 b0 = *(const float4*)&Bs[k][tx*4];
            float4 b1 = *(const float4*)&Bs[k][64 + tx*4];
            float av2[8] = {a0.x,a0.y,a0.z,a0.w,a1.x,a1.y,a1.z,a1.w};
            float bv2[8] = {b0.x,b0.y,b0.z,b0.w,b1.x,b1.y,b1.z,b1.w};
            #pragma unroll
            for (int i = 0; i < 8; ++i)
                #pragma unroll
                for (int j = 0; j < 8; ++j)
                    acc[i][j] = fmaf(av2[i], bv2[j], acc[i][j]);
        }
        __syncthreads();
    }
    unsigned long long (*red)[16] = (unsigned long long (*)[16])smem_raw;
    float cj[8];
    int   jglob[8];
    #pragma unroll
    for (int j = 0; j < 8; ++j) {
        int c = (j < 4) ? (tx*4 + j) : (64 + tx*4 + (j - 4));
        jglob[j] = bn + c;
        cj[j]    = psq[bn + c];
    }
    #pragma unroll
    for (int i = 0; i < 8; ++i) {
        float bestv = 0.f; unsigned bidx = 0u; bool first = true;
        #pragma unroll
        for (int j = 0; j < 8; ++j) {
            float s = fmaf(-2.f, acc[i][j], cj[j]);
            if (first || s < bestv) { bestv = s; bidx = (unsigned)jglob[j]; first = false; }
        }
        unsigned u = fkey(bestv);
        red[ty*8 + i][tx] = ((unsigned long long)u << 32) | (unsigned long long)bidx;
    }
    __syncthreads();
    if (tid < BM1) {
        unsigned long long m = red[tid][0];
        #pragma unroll
        for (int t = 1; t < 16; ++t) m = umin64(m, red[tid][t]);
        atomicMin(&minpack[bm + tid], m);
    }
}

__global__ void gather_kernel(const float* __restrict__ P,
                              const unsigned long long* __restrict__ minpack,
                              float* __restrict__ out) {
    int row = blockIdx.x;
    unsigned idx = (unsigned)(minpack[row] & 0xFFFFFFFFull);
    int lane = threadIdx.x;
    ((float4*)(out + (size_t)row * ND))[lane] =
        ((const float4*)(P + (size_t)idx * ND))[lane];
}

// ------------------------------------------------------------------- launch
extern "C" void kernel_launch(void* const* d_in, const int* in_sizes, int n_in,
                              void* d_out, int out_size, void* d_ws, size_t ws_size,
                              hipStream_t stream) {
    const float* X = (const float*)d_in[0];
    const float* P = (const float*)d_in[1];
    float* out = (float*)d_out;
    char* w = (char*)d_ws;

    if (ws_size >= WS_NEED) {
        float* psq = (float*)(w + OFF_PSQ);
        __bf16* Xb = (__bf16*)(w + OFF_XB);
        __bf16* Pb = (__bf16*)(w + OFF_PB);
        unsigned* blockmin = (unsigned*)(w + OFF_BM);

        prep_kernel<<<(NP + NB) / 4, 256, 0, stream>>>(X, P, psq, Xb, Pb);
        nn_alds_kernel<<<(NB / 128) * NSPLIT, 512, 0, stream>>>(Xb, Pb, psq,
                                                                blockmin);
        rescore_wave_kernel<<<NB / 8, 512, 0, stream>>>(X, P, psq, blockmin, out);
    } else {
        float* psq = (float*)w;
        unsigned long long* minpack = (unsigned long long*)(w + (size_t)NP * 4);
        psq_init_kernel<<<NP / 4, 256, 0, stream>>>(P, psq, minpack);
        dim3 grid(NP / BN1, NB / BM1);
        nn_main_kernel<<<grid, dim3(256), 0, stream>>>(X, P, psq, minpack);
        gather_kernel<<<NB, 64, 0, stream>>>(P, minpack, out);
    }
}